// Round 10
// baseline (21.606 us; speedup 1.0000x reference)
//
// R10 = R9 kernel resubmitted verbatim (R9 died to UnresponsiveContainer before
// any measurement; no data to act on — same policy as R2->R3, R5->R6).
#include <hip/hip_runtime.h>

typedef __bf16 bf16x8 __attribute__((ext_vector_type(8)));
typedef float  f32x4  __attribute__((ext_vector_type(4)));

#define S_ 128
#define N_ 8
#define A_ 10
#define E_ 64
#define SS_ 32
#define BT_ 1024

__device__ __forceinline__ unsigned rotl32(unsigned v, int n){ return (v<<n)|(v>>(32-n)); }

// Threefry-2x32, 20 rounds, standard JAX constants. (Bit-exact, verified R1-R8.)
__device__ __forceinline__ void threefry2x32(unsigned k0, unsigned k1,
                                             unsigned x0, unsigned x1,
                                             unsigned &o0, unsigned &o1){
  const unsigned ks2 = k0 ^ k1 ^ 0x1BD11BDAu;
  x0 += k0; x1 += k1;
  x0+=x1; x1=rotl32(x1,13); x1^=x0;
  x0+=x1; x1=rotl32(x1,15); x1^=x0;
  x0+=x1; x1=rotl32(x1,26); x1^=x0;
  x0+=x1; x1=rotl32(x1, 6); x1^=x0;
  x0+=k1; x1+=ks2+1u;
  x0+=x1; x1=rotl32(x1,17); x1^=x0;
  x0+=x1; x1=rotl32(x1,29); x1^=x0;
  x0+=x1; x1=rotl32(x1,16); x1^=x0;
  x0+=x1; x1=rotl32(x1,24); x1^=x0;
  x0+=ks2; x1+=k0+2u;
  x0+=x1; x1=rotl32(x1,13); x1^=x0;
  x0+=x1; x1=rotl32(x1,15); x1^=x0;
  x0+=x1; x1=rotl32(x1,26); x1^=x0;
  x0+=x1; x1=rotl32(x1, 6); x1^=x0;
  x0+=k0; x1+=k1+3u;
  x0+=x1; x1=rotl32(x1,17); x1^=x0;
  x0+=x1; x1=rotl32(x1,29); x1^=x0;
  x0+=x1; x1=rotl32(x1,16); x1^=x0;
  x0+=x1; x1=rotl32(x1,24); x1^=x0;
  x0+=k1; x1+=ks2+4u;
  x0+=x1; x1=rotl32(x1,13); x1^=x0;
  x0+=x1; x1=rotl32(x1,15); x1^=x0;
  x0+=x1; x1=rotl32(x1,26); x1^=x0;
  x0+=x1; x1=rotl32(x1, 6); x1^=x0;
  x0+=ks2; x1+=k0+5u;
  o0=x0; o1=x1;
}

__global__ __launch_bounds__(256, 4) void shapley_kernel(
    const float* __restrict__ states,    // (BT,128)
    const float* __restrict__ agent_qs,  // (BT,A=10,N=8)
    const float* __restrict__ W1,        // (208,64)
    const float* __restrict__ b1,        // (64)
    const float* __restrict__ W2,        // (64,64)
    const float* __restrict__ b2,        // (64)
    const float* __restrict__ Wa,        // (64,1)
    const float* __restrict__ ba,        // (1)
    const float* __restrict__ Wv1,       // (128,64)
    const float* __restrict__ bv1,       // (64)
    const float* __restrict__ Wv2,       // (64,1)
    const float* __restrict__ bv2,       // (1)
    const int*   __restrict__ rng,       // (1)
    float* __restrict__ out)             // (BT,8)
{
  __shared__ __bf16  c_lT[E_*64];          // 8 KB  c^T [e][(p,g)] bf16 swizzled
  __shared__ __bf16  w2_l[E_*E_];          // 8 KB  W2^T [n][k] bf16 swizzled
  __shared__ __bf16  h1_l[4*2048];         // 16 KB per-wave 32 rows [r][e] swizzled
  __shared__ float   sp_part[4][E_];       // state-proj partials (4-way wave split)
  __shared__ float   vp_part[4][E_];       // value-proj partials
  __shared__ unsigned char gmap_l[4*64];   // [wave][sample][pos] -> agent
  __shared__ float   contrib_l[4*64];      // [wave][sample][agent]

  const int bt   = blockIdx.x;
  const int tid  = threadIdx.x;
  const int w    = tid >> 6;
  const int lane = tid & 63;
  const int Lg   = lane >> 4;              // 16-lane group id
  const int l15  = lane & 15;

  // ================= staging (single barrier at the end) =================

  // --- sort FIRST: only dependency is rng[0] (1 scalar load); gmap write
  //     retires with maximal lead. lane = (si = lane>>3, j = lane&7). [verbatim]
  {
    const unsigned k1 = (unsigned)rng[0];
    unsigned cnt = ((unsigned)(bt*SS_ + w + 4*(lane >> 3)) << 3) + (unsigned)(lane & 7);
    unsigned o0, o1;
    threefry2x32(0u, k1, 0u, cnt, o0, o1);
    const unsigned comp = (((o0 ^ o1) >> 9) << 3) | (unsigned)(lane & 7);
    int rank = 0;
    #pragma unroll
    for (int d = 1; d < 8; ++d) {
      unsigned oc = (unsigned)__shfl_xor((int)comp, d, 8);
      rank += (oc < comp) ? 1 : 0;
    }
    gmap_l[w*64 + (lane >> 3)*8 + rank] = (unsigned char)(lane & 7);
  }

  // --- c[p][g][e] = sum_a aq[a,g]*W1q[p,a,e] (f32 acc), bf16 to c_lT [e][combo]
  //     XOR-swizzled; wave owns combos 16w..16w+15 (p = 2w, 2w+1). No spb fold.
  {
    const float* aqb = agent_qs + bt*(A_*N_);
    const float* w1q = W1 + (S_ + 2*w*A_)*E_ + lane;
    float acc[16];
    #pragma unroll
    for (int j = 0; j < 16; ++j) acc[j] = 0.f;
    #pragma unroll
    for (int a = 0; a < A_; ++a) {
      const float4 aq0 = *reinterpret_cast<const float4*>(aqb + a*N_);
      const float4 aq1 = *reinterpret_cast<const float4*>(aqb + a*N_ + 4);
      const float w1q0 = w1q[a*E_];
      const float w1q1 = w1q[(A_ + a)*E_];
      acc[0] = fmaf(aq0.x, w1q0, acc[0]);  acc[1] = fmaf(aq0.y, w1q0, acc[1]);
      acc[2] = fmaf(aq0.z, w1q0, acc[2]);  acc[3] = fmaf(aq0.w, w1q0, acc[3]);
      acc[4] = fmaf(aq1.x, w1q0, acc[4]);  acc[5] = fmaf(aq1.y, w1q0, acc[5]);
      acc[6] = fmaf(aq1.z, w1q0, acc[6]);  acc[7] = fmaf(aq1.w, w1q0, acc[7]);
      acc[8]  = fmaf(aq0.x, w1q1, acc[8]);   acc[9]  = fmaf(aq0.y, w1q1, acc[9]);
      acc[10] = fmaf(aq0.z, w1q1, acc[10]);  acc[11] = fmaf(aq0.w, w1q1, acc[11]);
      acc[12] = fmaf(aq1.x, w1q1, acc[12]);  acc[13] = fmaf(aq1.y, w1q1, acc[13]);
      acc[14] = fmaf(aq1.z, w1q1, acc[14]);  acc[15] = fmaf(aq1.w, w1q1, acc[15]);
    }
    bf16x8 pk0, pk1;
    #pragma unroll
    for (int j = 0; j < 8; ++j) { pk0[j] = (__bf16)acc[j]; pk1[j] = (__bf16)acc[8+j]; }
    const int base = lane*128 + 32*w;          // byte offset of combo 16w in row e=lane
    const int sw   = (lane & 7) << 4;
    *reinterpret_cast<bf16x8*>(reinterpret_cast<char*>(c_lT) + ((base)      ^ sw)) = pk0;
    *reinterpret_cast<bf16x8*>(reinterpret_cast<char*>(c_lT) + ((base + 16) ^ sw)) = pk1;
  }

  // --- W2 -> bf16, transposed [n][k], XOR-swizzled (dwordx4 global reads)
  {
    const int f0   = (tid & 15) * 4;
    const int erow = tid >> 4;
    #pragma unroll
    for (int i = 0; i < 4; ++i) {
      const int e = erow + 16*i;
      const float4 wv = *reinterpret_cast<const float4*>(W2 + e*E_ + f0);
      #pragma unroll
      for (int q = 0; q < 4; ++q) {
        const int f = f0 + q;
        const int byte = (f*128 + e*2) ^ ((f & 7) << 4);
        w2_l[byte >> 1] = (__bf16)((q == 0) ? wv.x : (q == 1) ? wv.y : (q == 2) ? wv.z : wv.w);
      }
    }
  }

  // --- state + value projections: 4-way wave split, 2-way chain split (16-deep)
  {
    const float* st = states + bt*S_;
    const int k0 = w*32;
    float sacc0 = (w == 0) ? b1[lane]  : 0.f, sacc1 = 0.f;
    float vacc0 = (w == 0) ? bv1[lane] : 0.f, vacc1 = 0.f;
    #pragma unroll 8
    for (int k = k0; k < k0 + 16; ++k) {
      const float sv = st[k];
      sacc0 = fmaf(sv, W1 [k*E_ + lane], sacc0);
      vacc0 = fmaf(sv, Wv1[k*E_ + lane], vacc0);
    }
    #pragma unroll 8
    for (int k = k0 + 16; k < k0 + 32; ++k) {
      const float sv = st[k];
      sacc1 = fmaf(sv, W1 [k*E_ + lane], sacc1);
      vacc1 = fmaf(sv, Wv1[k*E_ + lane], vacc1);
    }
    sp_part[w][lane] = sacc0 + sacc1;
    vp_part[w][lane] = vacc0 + vacc1;
  }

  // wave-0 tail constants
  float wv2r = 0.f, tailc = 0.f;
  if (w == 0) { wv2r = Wv2[lane]; tailc = ba[0] + bv2[0]; }

  // epilogue constants
  float b2r[4], war[4];
  #pragma unroll
  for (int nt = 0; nt < 4; ++nt) {
    b2r[nt] = b2[nt*16 + l15];
    war[nt] = Wa[nt*16 + l15];
  }

  __syncthreads();   // sync1 (the only staging barrier)

  // spb per lane-column: spb_r[nt] for e = nt*16 + l15
  float spb_r[4];
  #pragma unroll
  for (int nt = 0; nt < 4; ++nt) {
    const int e = nt*16 + l15;
    spb_r[nt] = (sp_part[0][e] + sp_part[1][e]) + (sp_part[2][e] + sp_part[3][e]);
  }

  const int wbase = w*4096;   // byte base of this wave's h1 region
  const int pval  = lane & 7; // row p for M-frags (m&7 == lane&7)

  #pragma unroll
  for (int pp = 0; pp < 2; ++pp) {
    // --- c B-frags [kt][nt]: lane holds c[(p',g)=kt*32+Lg*8+j][e=nt*16+l15]
    bf16x8 cfr[2][4];
    #pragma unroll
    for (int kt = 0; kt < 2; ++kt)
      #pragma unroll
      for (int nt = 0; nt < 4; ++nt) {
        const int e = nt*16 + l15;
        const int byte = (e*128 + kt*64 + Lg*16) ^ ((e & 7) << 4);
        cfr[kt][nt] = *reinterpret_cast<const bf16x8*>(reinterpret_cast<const char*>(c_lT) + byte);
      }

    // --- gmap rows for this pass's two 16-row tiles (A-frag m = mt2*16+l15)
    const int sA = pp*4 + 0*2 + (l15 >> 3);
    const int sB = pp*4 + 1*2 + (l15 >> 3);
    const uint2 gA = *reinterpret_cast<const uint2*>(&gmap_l[w*64 + sA*8]);
    const uint2 gB = *reinterpret_cast<const uint2*>(&gmap_l[w*64 + sB*8]);

    // --- GEMM1: D1 = M @ c  (16 MFMAs); M one-hot frags built in registers
    f32x4 d1[2][4];
    #pragma unroll
    for (int mt2 = 0; mt2 < 2; ++mt2)
      #pragma unroll
      for (int nt = 0; nt < 4; ++nt)
        d1[mt2][nt] = (f32x4){0.f, 0.f, 0.f, 0.f};
    #pragma unroll
    for (int mt2 = 0; mt2 < 2; ++mt2) {
      const uint2 gj = mt2 ? gB : gA;
      #pragma unroll
      for (int kt = 0; kt < 2; ++kt) {
        const unsigned gm = ((kt ? gj.y : gj.x) >> (Lg*8)) & 0xffu;  // perm agent at p'
        const unsigned full = ((kt*4 + Lg) <= pval) ? (0x3F80u << ((gm & 1u) << 4)) : 0u;
        uint4 mm;
        mm.x = ((gm >> 1) == 0u) ? full : 0u;
        mm.y = ((gm >> 1) == 1u) ? full : 0u;
        mm.z = ((gm >> 1) == 2u) ? full : 0u;
        mm.w = ((gm >> 1) == 3u) ? full : 0u;
        const bf16x8 mfrag = __builtin_bit_cast(bf16x8, mm);
        #pragma unroll
        for (int nt = 0; nt < 4; ++nt)
          d1[mt2][nt] = __builtin_amdgcn_mfma_f32_16x16x32_bf16(mfrag, cfr[kt][nt], d1[mt2][nt], 0, 0, 0);
      }
    }

    // --- h1 = relu(D1 + spb) -> LDS rows [r2][e] bf16 swizzled
    #pragma unroll
    for (int mt2 = 0; mt2 < 2; ++mt2)
      #pragma unroll
      for (int nt = 0; nt < 4; ++nt)
        #pragma unroll
        for (int reg = 0; reg < 4; ++reg) {
          const int r2 = mt2*16 + Lg*4 + reg;
          const int e  = nt*16 + l15;
          const int byte = ((r2 << 7) + (e << 1)) ^ ((r2 & 7) << 4);
          h1_l[(wbase + byte) >> 1] = (__bf16)fmaxf(d1[mt2][nt][reg] + spb_r[nt], 0.f);
        }

    // same-wave LDS write->read ordering
    asm volatile("s_waitcnt lgkmcnt(0)" ::: "memory");
    __builtin_amdgcn_sched_barrier(0);

    // --- A fragments of h1: lane holds A[mt2*16+l15][kt*32+Lg*8+j]
    bf16x8 afr[2][2];
    #pragma unroll
    for (int mt2 = 0; mt2 < 2; ++mt2)
      #pragma unroll
      for (int kt = 0; kt < 2; ++kt) {
        const int lr = mt2*16 + l15;
        const int byte = ((lr << 7) + (kt*32 + Lg*8)*2) ^ ((lr & 7) << 4);
        afr[mt2][kt] = *reinterpret_cast<const bf16x8*>(&h1_l[(wbase + byte) >> 1]);
      }

    // --- W2 B-frags (per pass reload keeps VGPR < 128)
    bf16x8 bfr[2][4];
    #pragma unroll
    for (int kt = 0; kt < 2; ++kt)
      #pragma unroll
      for (int nt = 0; nt < 4; ++nt) {
        const int n = nt*16 + l15;
        const int byte = (n*128 + (kt*32 + Lg*8)*2) ^ ((n & 7) << 4);
        bfr[kt][nt] = *reinterpret_cast<const bf16x8*>(&w2_l[byte >> 1]);
      }

    // --- GEMM2: 16 MFMAs
    f32x4 acc4[2][4];
    #pragma unroll
    for (int mt2 = 0; mt2 < 2; ++mt2)
      #pragma unroll
      for (int nt = 0; nt < 4; ++nt) {
        acc4[mt2][nt] = (f32x4){0.f, 0.f, 0.f, 0.f};
        acc4[mt2][nt] = __builtin_amdgcn_mfma_f32_16x16x32_bf16(afr[mt2][0], bfr[0][nt], acc4[mt2][nt], 0, 0, 0);
        acc4[mt2][nt] = __builtin_amdgcn_mfma_f32_16x16x32_bf16(afr[mt2][1], bfr[1][nt], acc4[mt2][nt], 0, 0, 0);
      }

    // --- epilogue: h2=relu(D+b2); rowsum of h2*Wa; route to (sample,agent)
    #pragma unroll
    for (int mt2 = 0; mt2 < 2; ++mt2)
      #pragma unroll
      for (int reg = 0; reg < 4; ++reg) {
        float partv = 0.f;
        #pragma unroll
        for (int nt = 0; nt < 4; ++nt)
          partv = fmaf(fmaxf(acc4[mt2][nt][reg] + b2r[nt], 0.f), war[nt], partv);
        partv += __shfl_xor(partv, 1, 16);
        partv += __shfl_xor(partv, 2, 16);
        partv += __shfl_xor(partv, 4, 16);
        partv += __shfl_xor(partv, 8, 16);
        if (l15 == 0) {
          const int r2 = mt2*16 + Lg*4 + reg;          // D: row
          const int r  = pp*32 + r2;                   // global row = s*8+p
          const int g  = gmap_l[w*64 + r];
          contrib_l[w*64 + (r >> 3)*8 + g] = partv;    // unique (w,s,g)
        }
      }

    // pass-1 h1 writes may not overtake pass-0 A-frag reads
    asm volatile("s_waitcnt lgkmcnt(0)" ::: "memory");
    __builtin_amdgcn_sched_barrier(0);
  }

  __syncthreads();

  // --- final: mean over 32 (w,s) per agent + value head (wave 0)
  if (w == 0) {
    float s = contrib_l[lane] + contrib_l[lane + 64]
            + contrib_l[lane + 128] + contrib_l[lane + 192];
    s += __shfl_xor(s, 8, 64);
    s += __shfl_xor(s, 16, 64);
    s += __shfl_xor(s, 32, 64);
    float pv = fmaxf((vp_part[0][lane] + vp_part[1][lane])
                   + (vp_part[2][lane] + vp_part[3][lane]), 0.f) * wv2r;
    #pragma unroll
    for (int off = 32; off >= 1; off >>= 1) pv += __shfl_xor(pv, off, 64);
    if (lane < N_) out[bt*N_ + lane] = s*(1.f/SS_) + pv + tailc;
  }
}

extern "C" void kernel_launch(void* const* d_in, const int* in_sizes, int n_in,
                              void* d_out, int out_size, void* d_ws, size_t ws_size,
                              hipStream_t stream) {
  const float* states   = (const float*)d_in[0];
  const float* agent_qs = (const float*)d_in[1];
  const float* W1  = (const float*)d_in[2];
  const float* b1  = (const float*)d_in[3];
  const float* W2  = (const float*)d_in[4];
  const float* b2  = (const float*)d_in[5];
  const float* Wa  = (const float*)d_in[6];
  const float* ba  = (const float*)d_in[7];
  const float* Wv1 = (const float*)d_in[8];
  const float* bv1 = (const float*)d_in[9];
  const float* Wv2 = (const float*)d_in[10];
  const float* bv2 = (const float*)d_in[11];
  const int*   rng = (const int*)d_in[12];
  float* out = (float*)d_out;

  hipLaunchKernelGGL(shapley_kernel, dim3(BT_), dim3(256), 0, stream,
                     states, agent_qs, W1, b1, W2, b2, Wa, ba, Wv1, bv1, Wv2, bv2,
                     rng, out);
}

// Round 11
// 19.142 us; speedup vs baseline: 1.1287x; 1.1287x over previous
//
// R11 = R7 kernel resubmitted verbatim (best measured: 19.07us) as a same-session
// A/B against R10 (21.6us). R7-R10 span four structures within +-1.3us -> interior
// is not the binding constraint; occupancy capped at 4 waves/SIMD by VGPR quantum;
// suspected low-clock replay window (each replay follows a 268MB/39us fill).
#include <hip/hip_runtime.h>

typedef __bf16 bf16x8 __attribute__((ext_vector_type(8)));
typedef float  f32x4  __attribute__((ext_vector_type(4)));

#define S_ 128
#define N_ 8
#define A_ 10
#define E_ 64
#define SS_ 32
#define BT_ 1024

__device__ __forceinline__ unsigned rotl32(unsigned v, int n){ return (v<<n)|(v>>(32-n)); }

// Threefry-2x32, 20 rounds, standard JAX constants. (Bit-exact, verified R1-R10.)
__device__ __forceinline__ void threefry2x32(unsigned k0, unsigned k1,
                                             unsigned x0, unsigned x1,
                                             unsigned &o0, unsigned &o1){
  const unsigned ks2 = k0 ^ k1 ^ 0x1BD11BDAu;
  x0 += k0; x1 += k1;
  x0+=x1; x1=rotl32(x1,13); x1^=x0;
  x0+=x1; x1=rotl32(x1,15); x1^=x0;
  x0+=x1; x1=rotl32(x1,26); x1^=x0;
  x0+=x1; x1=rotl32(x1, 6); x1^=x0;
  x0+=k1; x1+=ks2+1u;
  x0+=x1; x1=rotl32(x1,17); x1^=x0;
  x0+=x1; x1=rotl32(x1,29); x1^=x0;
  x0+=x1; x1=rotl32(x1,16); x1^=x0;
  x0+=x1; x1=rotl32(x1,24); x1^=x0;
  x0+=ks2; x1+=k0+2u;
  x0+=x1; x1=rotl32(x1,13); x1^=x0;
  x0+=x1; x1=rotl32(x1,15); x1^=x0;
  x0+=x1; x1=rotl32(x1,26); x1^=x0;
  x0+=x1; x1=rotl32(x1, 6); x1^=x0;
  x0+=k0; x1+=k1+3u;
  x0+=x1; x1=rotl32(x1,17); x1^=x0;
  x0+=x1; x1=rotl32(x1,29); x1^=x0;
  x0+=x1; x1=rotl32(x1,16); x1^=x0;
  x0+=x1; x1=rotl32(x1,24); x1^=x0;
  x0+=k1; x1+=ks2+4u;
  x0+=x1; x1=rotl32(x1,13); x1^=x0;
  x0+=x1; x1=rotl32(x1,15); x1^=x0;
  x0+=x1; x1=rotl32(x1,26); x1^=x0;
  x0+=x1; x1=rotl32(x1, 6); x1^=x0;
  x0+=ks2; x1+=k0+5u;
  o0=x0; o1=x1;
}

__global__ __launch_bounds__(256, 4) void shapley_kernel(
    const float* __restrict__ states,    // (BT,128)
    const float* __restrict__ agent_qs,  // (BT,A=10,N=8)
    const float* __restrict__ W1,        // (208,64)
    const float* __restrict__ b1,        // (64)
    const float* __restrict__ W2,        // (64,64)
    const float* __restrict__ b2,        // (64)
    const float* __restrict__ Wa,        // (64,1)
    const float* __restrict__ ba,        // (1)
    const float* __restrict__ Wv1,       // (128,64)
    const float* __restrict__ bv1,       // (64)
    const float* __restrict__ Wv2,       // (64,1)
    const float* __restrict__ bv2,       // (1)
    const int*   __restrict__ rng,       // (1)
    float* __restrict__ out)             // (BT,8)
{
  __shared__ float   c_l[N_*N_*E_];        // 16 KB fp32 c[p][g][e]
  __shared__ __bf16  h1_l[4*2048];         // 16 KB: per-wave 4KB (32 rows);
                                           //   bytes 0..8191 overlaid with W2^T at staging
  __shared__ float   sp_part[4][E_];       // state-proj partials (4-way k-split)
  __shared__ float   vp_part[4][E_];       // value-proj partials
  __shared__ unsigned char gmap_l[4*64];   // [wave][sample][pos] -> agent
  __shared__ float   contrib_l[4*64];      // [wave][sample][agent]

  const int bt   = blockIdx.x;
  const int tid  = threadIdx.x;
  const int w    = tid >> 6;
  const int lane = tid & 63;

  // ================= staging phase (everything before sync1) =================

  // --- c-table: c[p][g][e] = sum_a aq[a,g] * W1q[p,a,e]  (fp32, exact).
  // This wave owns p0=2w, p1=2w+1; acc[(i<<3)|g] in regs; aq rows via uniform
  // float4 (scalarized to s_load); 2 coalesced W1q loads per a (20 total).
  {
    const float* aqb = agent_qs + bt*(A_*N_);
    const float* w1q = W1 + (S_ + 2*w*A_)*E_ + lane;
    float acc[16];
    #pragma unroll
    for (int j = 0; j < 16; ++j) acc[j] = 0.f;
    #pragma unroll
    for (int a = 0; a < A_; ++a) {
      const float4 aq0 = *reinterpret_cast<const float4*>(aqb + a*N_);
      const float4 aq1 = *reinterpret_cast<const float4*>(aqb + a*N_ + 4);
      const float w1q0 = w1q[a*E_];
      const float w1q1 = w1q[(A_ + a)*E_];
      acc[0] = fmaf(aq0.x, w1q0, acc[0]);  acc[1] = fmaf(aq0.y, w1q0, acc[1]);
      acc[2] = fmaf(aq0.z, w1q0, acc[2]);  acc[3] = fmaf(aq0.w, w1q0, acc[3]);
      acc[4] = fmaf(aq1.x, w1q0, acc[4]);  acc[5] = fmaf(aq1.y, w1q0, acc[5]);
      acc[6] = fmaf(aq1.z, w1q0, acc[6]);  acc[7] = fmaf(aq1.w, w1q0, acc[7]);
      acc[8]  = fmaf(aq0.x, w1q1, acc[8]);   acc[9]  = fmaf(aq0.y, w1q1, acc[9]);
      acc[10] = fmaf(aq0.z, w1q1, acc[10]);  acc[11] = fmaf(aq0.w, w1q1, acc[11]);
      acc[12] = fmaf(aq1.x, w1q1, acc[12]);  acc[13] = fmaf(aq1.y, w1q1, acc[13]);
      acc[14] = fmaf(aq1.z, w1q1, acc[14]);  acc[15] = fmaf(aq1.w, w1q1, acc[15]);
    }
    #pragma unroll
    for (int j = 0; j < 16; ++j)
      c_l[((2*w)*N_ + j)*E_ + lane] = acc[j];   // j = (i<<3)|g -> combo 16w+j
  }

  // --- W2 -> bf16, transposed [n][k], XOR-swizzled, into the h1 overlay region.
  // dwordx4 reads: thread (erow=tid>>4, fgrp=tid&15) loads W2[e][4f..4f+3].
  {
    const int f0   = (tid & 15) * 4;
    const int erow = tid >> 4;
    #pragma unroll
    for (int i = 0; i < 4; ++i) {
      const int e = erow + 16*i;
      const float4 wv = *reinterpret_cast<const float4*>(W2 + e*E_ + f0);
      #pragma unroll
      for (int q = 0; q < 4; ++q) {
        const int f = f0 + q;
        const int byte = (f*128 + e*2) ^ ((f & 7) << 4);
        h1_l[byte >> 1] = (__bf16)((q == 0) ? wv.x : (q == 1) ? wv.y : (q == 2) ? wv.z : wv.w);
      }
    }
  }

  // --- state + value projections: 4-way k-split across waves (32-deep chains)
  {
    const float* st = states + bt*S_;
    const int k0 = w*32;
    float sacc = (w == 0) ? b1[lane]  : 0.f;
    float vacc = (w == 0) ? bv1[lane] : 0.f;
    #pragma unroll 8
    for (int k = k0; k < k0 + 32; ++k) {
      const float sv = st[k];                       // uniform -> s_load
      sacc = fmaf(sv, W1 [k*E_ + lane], sacc);
      vacc = fmaf(sv, Wv1[k*E_ + lane], vacc);
    }
    sp_part[w][lane] = sacc;
    vp_part[w][lane] = vacc;
  }

  // wave-0 tail constants
  float wv2r = 0.f, tailc = 0.f;
  if (w == 0) { wv2r = Wv2[lane]; tailc = ba[0] + bv2[0]; }

  // epilogue constants (all waves)
  float b2r[4], war[4];
  #pragma unroll
  for (int nt = 0; nt < 4; ++nt) {
    b2r[nt] = b2[nt*16 + (lane & 15)];
    war[nt] = Wa[nt*16 + (lane & 15)];
  }

  // lane-parallel sort: lane = (si = lane>>3, j = lane&7)   [verbatim R4/R6]
  {
    const unsigned k1 = (unsigned)rng[0];
    unsigned cnt = ((unsigned)(bt*SS_ + w + 4*(lane >> 3)) << 3) + (unsigned)(lane & 7);
    unsigned o0, o1;
    threefry2x32(0u, k1, 0u, cnt, o0, o1);
    const unsigned comp = (((o0 ^ o1) >> 9) << 3) | (unsigned)(lane & 7);
    int rank = 0;
    #pragma unroll
    for (int d = 1; d < 8; ++d) {
      unsigned oc = (unsigned)__shfl_xor((int)comp, d, 8);
      rank += (oc < comp) ? 1 : 0;
    }
    gmap_l[w*64 + (lane >> 3)*8 + rank] = (unsigned char)(lane & 7);
  }

  __syncthreads();   // sync1: c_l, overlay W2, partials, gmap all visible

  // B fragments from overlay: B[k][n], lane holds B[kt*32+(l>>4)*8+j][l&15]
  bf16x8 bfr[2][4];
  #pragma unroll
  for (int kt = 0; kt < 2; ++kt)
    #pragma unroll
    for (int nt = 0; nt < 4; ++nt) {
      const int n = nt*16 + (lane & 15);
      const int byte = (n*128 + (kt*32 + (lane >> 4)*8)*2) ^ ((n & 7) << 4);
      bfr[kt][nt] = *reinterpret_cast<const bf16x8*>(&h1_l[byte >> 1]);
    }

  const float spb = (sp_part[0][lane] + sp_part[1][lane])
                  + (sp_part[2][lane] + sp_part[3][lane]);

  __syncthreads();   // sync2: all B-frag reads done before h1 overwrites overlay

  const int wbase = w*4096;   // byte base of this wave's h1 region

  #pragma unroll
  for (int pp = 0; pp < 2; ++pp) {
    // --- layer 1 (fp32 prefix) -> 32 h1 rows (samples pp*4..pp*4+3), bf16 swizzled
    #pragma unroll
    for (int si2 = 0; si2 < 4; ++si2) {
      const int si = pp*4 + si2;
      const uint2 gm = *reinterpret_cast<const uint2*>(&gmap_l[w*64 + si*8]);
      float acc = 0.f;
      #pragma unroll
      for (int p = 0; p < 8; ++p) {
        const unsigned g = ((p < 4 ? (gm.x >> (8*p)) : (gm.y >> (8*(p - 4)))) & 0xffu);
        acc += c_l[((p << 3) + (int)g)*E_ + lane];
        const float h1 = fmaxf(acc + spb, 0.f);
        const int r2 = (si2 << 3) + p;
        const int byte = ((r2 << 7) + (lane << 1)) ^ ((r2 & 7) << 4);
        h1_l[(wbase + byte) >> 1] = (__bf16)h1;
      }
    }

    // same-wave LDS write->read ordering (no cross-wave barrier needed)
    asm volatile("s_waitcnt lgkmcnt(0)" ::: "memory");
    __builtin_amdgcn_sched_barrier(0);

    // --- A fragments: lane holds A[mt2*16+(l&15)][kt*32+(l>>4)*8+j]
    bf16x8 afr[2][2];
    #pragma unroll
    for (int mt2 = 0; mt2 < 2; ++mt2)
      #pragma unroll
      for (int kt = 0; kt < 2; ++kt) {
        const int lr = mt2*16 + (lane & 15);
        const int byte = ((lr << 7) + (kt*32 + (lane >> 4)*8)*2) ^ ((lr & 7) << 4);
        afr[mt2][kt] = *reinterpret_cast<const bf16x8*>(&h1_l[(wbase + byte) >> 1]);
      }

    // --- 32x64x64 GEMM: 16 MFMAs, fp32 accumulate
    f32x4 acc4[2][4];
    #pragma unroll
    for (int mt2 = 0; mt2 < 2; ++mt2)
      #pragma unroll
      for (int nt = 0; nt < 4; ++nt) {
        acc4[mt2][nt] = (f32x4){0.f, 0.f, 0.f, 0.f};
        acc4[mt2][nt] = __builtin_amdgcn_mfma_f32_16x16x32_bf16(afr[mt2][0], bfr[0][nt], acc4[mt2][nt], 0, 0, 0);
        acc4[mt2][nt] = __builtin_amdgcn_mfma_f32_16x16x32_bf16(afr[mt2][1], bfr[1][nt], acc4[mt2][nt], 0, 0, 0);
      }

    // --- epilogue: h2=relu(D+b2); rowsum of h2*Wa; route to (sample,agent)
    #pragma unroll
    for (int mt2 = 0; mt2 < 2; ++mt2)
      #pragma unroll
      for (int reg = 0; reg < 4; ++reg) {
        float partv = 0.f;
        #pragma unroll
        for (int nt = 0; nt < 4; ++nt)
          partv = fmaf(fmaxf(acc4[mt2][nt][reg] + b2r[nt], 0.f), war[nt], partv);
        partv += __shfl_xor(partv, 1, 16);
        partv += __shfl_xor(partv, 2, 16);
        partv += __shfl_xor(partv, 4, 16);
        partv += __shfl_xor(partv, 8, 16);
        if ((lane & 15) == 0) {
          const int r2 = mt2*16 + (lane >> 4)*4 + reg;   // D: row=(lane>>4)*4+reg
          const int r  = pp*32 + r2;                     // global row = s*8+p
          const int g  = gmap_l[w*64 + r];
          contrib_l[w*64 + (r >> 3)*8 + g] = partv;      // unique (w,s,g)
        }
      }

    // pass-1 h1 writes may not overtake pass-0 A-frag reads:
    asm volatile("s_waitcnt lgkmcnt(0)" ::: "memory");
    __builtin_amdgcn_sched_barrier(0);
  }

  __syncthreads();

  // --- final: mean over 32 (w,s) per agent + value head (wave 0)
  if (w == 0) {
    float s = contrib_l[lane] + contrib_l[lane + 64]
            + contrib_l[lane + 128] + contrib_l[lane + 192];
    s += __shfl_xor(s, 8, 64);
    s += __shfl_xor(s, 16, 64);
    s += __shfl_xor(s, 32, 64);
    float pv = fmaxf((vp_part[0][lane] + vp_part[1][lane])
                   + (vp_part[2][lane] + vp_part[3][lane]), 0.f) * wv2r;
    #pragma unroll
    for (int off = 32; off >= 1; off >>= 1) pv += __shfl_xor(pv, off, 64);
    if (lane < N_) out[bt*N_ + lane] = s*(1.f/SS_) + pv + tailc;
  }
}

extern "C" void kernel_launch(void* const* d_in, const int* in_sizes, int n_in,
                              void* d_out, int out_size, void* d_ws, size_t ws_size,
                              hipStream_t stream) {
  const float* states   = (const float*)d_in[0];
  const float* agent_qs = (const float*)d_in[1];
  const float* W1  = (const float*)d_in[2];
  const float* b1  = (const float*)d_in[3];
  const float* W2  = (const float*)d_in[4];
  const float* b2  = (const float*)d_in[5];
  const float* Wa  = (const float*)d_in[6];
  const float* ba  = (const float*)d_in[7];
  const float* Wv1 = (const float*)d_in[8];
  const float* bv1 = (const float*)d_in[9];
  const float* Wv2 = (const float*)d_in[10];
  const float* bv2 = (const float*)d_in[11];
  const int*   rng = (const int*)d_in[12];
  float* out = (float*)d_out;

  hipLaunchKernelGGL(shapley_kernel, dim3(BT_), dim3(256), 0, stream,
                     states, agent_qs, W1, b1, W2, b2, Wa, ba, Wv1, bv1, Wv2, bv2,
                     rng, out);
}